// Round 1
// baseline (923.836 us; speedup 1.0000x reference)
//
#include <hip/hip_runtime.h>
#include <math.h>

// ---------------- CSR build ----------------

__global__ __launch_bounds__(256) void hist_k(const int* __restrict__ dst, int* __restrict__ deg, int E) {
    int e = blockIdx.x * 256 + threadIdx.x;
    if (e < E) atomicAdd(&deg[dst[e]], 1);
}

__global__ __launch_bounds__(256) void scanA_k(const int* __restrict__ deg, int* __restrict__ rowptr,
                                               int* __restrict__ partials, int N) {
    __shared__ int sh[256];
    int t = threadIdx.x;
    int base = blockIdx.x * 1024 + t * 4;
    int v0 = 0, v1 = 0, v2 = 0, v3 = 0;
    if (base + 0 < N) v0 = deg[base + 0];
    if (base + 1 < N) v1 = deg[base + 1];
    if (base + 2 < N) v2 = deg[base + 2];
    if (base + 3 < N) v3 = deg[base + 3];
    sh[t] = v0 + v1 + v2 + v3;
    __syncthreads();
    for (int off = 1; off < 256; off <<= 1) {
        int add = (t >= off) ? sh[t - off] : 0;
        __syncthreads();
        sh[t] += add;
        __syncthreads();
    }
    int run = (t > 0) ? sh[t - 1] : 0;
    if (base + 0 < N) rowptr[base + 0] = run; run += v0;
    if (base + 1 < N) rowptr[base + 1] = run; run += v1;
    if (base + 2 < N) rowptr[base + 2] = run; run += v2;
    if (base + 3 < N) rowptr[base + 3] = run;
    if (t == 255) partials[blockIdx.x] = sh[255];
}

__global__ void scanB_k(int* partials, int nch) {
    if (threadIdx.x == 0 && blockIdx.x == 0) {
        int run = 0;
        for (int i = 0; i < nch; ++i) { int x = partials[i]; partials[i] = run; run += x; }
        partials[nch] = run;
    }
}

__global__ __launch_bounds__(256) void addoff_k(int* __restrict__ rowptr, const int* __restrict__ partials,
                                                int N, int nch) {
    int t = threadIdx.x;
    int off = partials[blockIdx.x];
    int base = blockIdx.x * 1024;
    for (int i = 0; i < 4; ++i) {
        int idx = base + t + i * 256;
        if (idx < N) rowptr[idx] += off;
    }
    if (blockIdx.x == 0 && t == 0) rowptr[N] = partials[nch];
}

__global__ __launch_bounds__(256) void scatter_k(const int* __restrict__ src, const int* __restrict__ dst,
                                                 const int* __restrict__ rowptr, int* __restrict__ cnt,
                                                 int* __restrict__ srcid, int E) {
    int e = blockIdx.x * 256 + threadIdx.x;
    if (e < E) {
        int d = dst[e];
        int pos = rowptr[d] + atomicAdd(&cnt[d], 1);
        srcid[pos] = src[e];
    }
}

// ---------------- fused Q/K/V/skip projection (SGEMM, cols = [Wq|Wk|Wv|Ws] = 416) ----------------

__global__ __launch_bounds__(256) void qkvs_k(const float* __restrict__ X, int Cin, int N,
    const float* __restrict__ Wq, const float* __restrict__ bq,
    const float* __restrict__ Wk, const float* __restrict__ bk,
    const float* __restrict__ Wv, const float* __restrict__ bv,
    const float* __restrict__ Ws, const float* __restrict__ bs,
    float* __restrict__ q, float* __restrict__ k, float* __restrict__ v, float* __restrict__ sk)
{
    __shared__ float As[64][32];
    __shared__ float Bs[32][64];
    int tid = threadIdx.x;
    int ty = tid >> 4, tx = tid & 15;
    int row0 = blockIdx.x * 64;
    int c0 = blockIdx.y * 64;
    float acc[4][4];
#pragma unroll
    for (int i = 0; i < 4; ++i)
#pragma unroll
        for (int j = 0; j < 4; ++j) acc[i][j] = 0.f;

    for (int k0 = 0; k0 < Cin; k0 += 32) {
#pragma unroll
        for (int i = 0; i < 2; ++i) {
            int f4 = tid + i * 256;
            int r = f4 >> 3;
            int kk = (f4 & 7) << 2;
            float4 val = make_float4(0.f, 0.f, 0.f, 0.f);
            int gr = row0 + r;
            if (gr < N) val = *(const float4*)(X + (size_t)gr * Cin + k0 + kk);
            *(float4*)&As[r][kk] = val;
        }
#pragma unroll
        for (int i = 0; i < 2; ++i) {
            int f4 = tid + i * 256;
            int kk = f4 >> 4;
            int cc = (f4 & 15) << 2;
            int gc = c0 + cc;
            float4 val = make_float4(0.f, 0.f, 0.f, 0.f);
            const float* W = nullptr; int ow = 0, cb = 0;
            if (gc < 128)      { W = Wq; ow = 128; cb = gc; }
            else if (gc < 256) { W = Wk; ow = 128; cb = gc - 128; }
            else if (gc < 384) { W = Wv; ow = 128; cb = gc - 256; }
            else if (gc < 416) { W = Ws; ow = 32;  cb = gc - 384; }
            if (W) val = *(const float4*)(W + (size_t)(k0 + kk) * ow + cb);
            *(float4*)&Bs[kk][cc] = val;
        }
        __syncthreads();
#pragma unroll
        for (int kb = 0; kb < 32; kb += 4) {
            float a[4][4], b[4][4];
#pragma unroll
            for (int i = 0; i < 4; ++i) {
                float4 t4 = *(const float4*)&As[ty * 4 + i][kb];
                a[i][0] = t4.x; a[i][1] = t4.y; a[i][2] = t4.z; a[i][3] = t4.w;
            }
#pragma unroll
            for (int j = 0; j < 4; ++j) {
                float4 t4 = *(const float4*)&Bs[kb + j][tx * 4];
                b[j][0] = t4.x; b[j][1] = t4.y; b[j][2] = t4.z; b[j][3] = t4.w;
            }
#pragma unroll
            for (int i = 0; i < 4; ++i)
#pragma unroll
                for (int j = 0; j < 4; ++j)
#pragma unroll
                    for (int c = 0; c < 4; ++c)
                        acc[i][c] += a[i][j] * b[j][c];
        }
        __syncthreads();
    }

    int gc = c0 + tx * 4;
    const float* bias = nullptr; float* dstp = nullptr; int ow = 0, cb = 0;
    if (gc < 128)      { bias = bq; dstp = q;  ow = 128; cb = gc; }
    else if (gc < 256) { bias = bk; dstp = k;  ow = 128; cb = gc - 128; }
    else if (gc < 384) { bias = bv; dstp = v;  ow = 128; cb = gc - 256; }
    else if (gc < 416) { bias = bs; dstp = sk; ow = 32;  cb = gc - 384; }
    if (dstp) {
        float b0 = bias[cb], b1 = bias[cb + 1], b2 = bias[cb + 2], b3 = bias[cb + 3];
#pragma unroll
        for (int i = 0; i < 4; ++i) {
            int gr = row0 + ty * 4 + i;
            if (gr < N) {
                float4 o = make_float4(acc[i][0] + b0, acc[i][1] + b1, acc[i][2] + b2, acc[i][3] + b3);
                *(float4*)(dstp + (size_t)gr * ow + cb) = o;
            }
        }
    }
}

// ---------------- per-node attention over CSR (online softmax) ----------------

__global__ __launch_bounds__(128) void attn_k(const float* __restrict__ q, const float* __restrict__ k,
    const float* __restrict__ v, const float* __restrict__ sk,
    const int* __restrict__ rowptr, const int* __restrict__ srcid,
    float* __restrict__ out, int N)
{
    int n = blockIdx.x;
    int t = threadIdx.x;
    float qt = q[(size_t)n * 128 + t];
    float acc = 0.f, m = -INFINITY, l = 0.f;
    int e0 = rowptr[n], e1 = rowptr[n + 1];
    const float scale = 0.17677669529663687f;  // 1/sqrt(32)
    for (int e = e0; e < e1; ++e) {
        int s = srcid[e];
        float kv = k[(size_t)s * 128 + t];
        float p = qt * kv;
        p += __shfl_xor(p, 16, 32);
        p += __shfl_xor(p, 8, 32);
        p += __shfl_xor(p, 4, 32);
        p += __shfl_xor(p, 2, 32);
        p += __shfl_xor(p, 1, 32);
        float logit = p * scale;
        float mn = fmaxf(m, logit);
        float ex = __expf(logit - mn);
        float sc = __expf(m - mn);
        float vv = v[(size_t)s * 128 + t];
        l = l * sc + ex;
        acc = acc * sc + ex * vv;
        m = mn;
    }
    float res = acc / fmaxf(l, 1e-16f);
    __shared__ float sh[128];
    sh[t] = res;
    __syncthreads();
    if (t < 32) {
        float o = (sh[t] + sh[t + 32] + sh[t + 64] + sh[t + 96]) * 0.25f + sk[(size_t)n * 32 + t];
        out[(size_t)n * 32 + t] = fmaxf(o, 0.f);
    }
}

// ---------------- global mean pool (batch is sorted) ----------------

__global__ __launch_bounds__(256) void pool_k(const float* __restrict__ h, const int* __restrict__ batch,
                                              float* __restrict__ out, int N)
{
    int g = blockIdx.x;
    int t = threadIdx.x;
    int lo = 0, hi = N;
    while (lo < hi) { int mid = (lo + hi) >> 1; if (batch[mid] < g) lo = mid + 1; else hi = mid; }
    int start = lo;
    lo = 0; hi = N;
    while (lo < hi) { int mid = (lo + hi) >> 1; if (batch[mid] < g + 1) lo = mid + 1; else hi = mid; }
    int end = lo;
    int c = t & 31, r0 = t >> 5;
    float s = 0.f;
    for (int r = start + r0; r < end; r += 8) s += h[(size_t)r * 32 + c];
    __shared__ float sh[256];
    sh[t] = s;
    __syncthreads();
    if (t < 32) {
        float tot = sh[t] + sh[t + 32] + sh[t + 64] + sh[t + 96]
                  + sh[t + 128] + sh[t + 160] + sh[t + 192] + sh[t + 224];
        float cnt = (float)(end - start);
        out[(size_t)g * 32 + t] = tot / fmaxf(cnt, 1.f);
    }
}

// ---------------- launch ----------------

extern "C" void kernel_launch(void* const* d_in, const int* in_sizes, int n_in,
                              void* d_out, int out_size, void* d_ws, size_t ws_size,
                              hipStream_t stream) {
    const float* x   = (const float*)d_in[0];
    const int* ei    = (const int*)d_in[1];
    const int* batch = (const int*)d_in[2];
    const float *Wq1 = (const float*)d_in[3],  *bq1 = (const float*)d_in[4];
    const float *Wk1 = (const float*)d_in[5],  *bk1 = (const float*)d_in[6];
    const float *Wv1 = (const float*)d_in[7],  *bv1 = (const float*)d_in[8];
    const float *Ws1 = (const float*)d_in[9],  *bs1 = (const float*)d_in[10];
    const float *Wq2 = (const float*)d_in[11], *bq2 = (const float*)d_in[12];
    const float *Wk2 = (const float*)d_in[13], *bk2 = (const float*)d_in[14];
    const float *Wv2 = (const float*)d_in[15], *bv2 = (const float*)d_in[16];
    const float *Ws2 = (const float*)d_in[17], *bs2 = (const float*)d_in[18];
    float* out = (float*)d_out;

    int N = in_sizes[0] / 128;
    int E = in_sizes[1] / 2;
    const int* src = ei;
    const int* dst = ei + E;

    char* ws = (char*)d_ws;
    size_t off = 0;
    auto alloc = [&](size_t bytes) -> void* {
        void* p = ws + off;
        off += (bytes + 255) & ~(size_t)255;
        return p;
    };
    int* deg      = (int*)alloc((size_t)N * 4);
    int* cnt      = (int*)alloc((size_t)N * 4);
    int* rowptr   = (int*)alloc(((size_t)N + 1) * 4);
    int* partials = (int*)alloc(4096);
    int* srcid    = (int*)alloc((size_t)E * 4);
    float* q      = (float*)alloc((size_t)N * 128 * 4);
    float* k      = (float*)alloc((size_t)N * 128 * 4);
    float* v      = (float*)alloc((size_t)N * 128 * 4);
    float* sk     = (float*)alloc((size_t)N * 32 * 4);
    float* h1     = (float*)alloc((size_t)N * 32 * 4);
    float* h2     = (float*)alloc((size_t)N * 32 * 4);

    hipMemsetAsync(deg, 0, (size_t)N * 4, stream);
    hipMemsetAsync(cnt, 0, (size_t)N * 4, stream);

    int nch = (N + 1023) / 1024;
    hist_k<<<(E + 255) / 256, 256, 0, stream>>>(dst, deg, E);
    scanA_k<<<nch, 256, 0, stream>>>(deg, rowptr, partials, N);
    scanB_k<<<1, 64, 0, stream>>>(partials, nch);
    addoff_k<<<nch, 256, 0, stream>>>(rowptr, partials, N, nch);
    scatter_k<<<(E + 255) / 256, 256, 0, stream>>>(src, dst, rowptr, cnt, srcid, E);

    dim3 g1((N + 63) / 64, 7);
    qkvs_k<<<g1, 256, 0, stream>>>(x, 128, N, Wq1, bq1, Wk1, bk1, Wv1, bv1, Ws1, bs1, q, k, v, sk);
    attn_k<<<N, 128, 0, stream>>>(q, k, v, sk, rowptr, srcid, h1, N);
    qkvs_k<<<g1, 256, 0, stream>>>(h1, 32, N, Wq2, bq2, Wk2, bk2, Wv2, bv2, Ws2, bs2, q, k, v, sk);
    attn_k<<<N, 128, 0, stream>>>(q, k, v, sk, rowptr, srcid, h2, N);
    pool_k<<<512, 256, 0, stream>>>(h2, batch, out, N);
}

// Round 3
// 846.401 us; speedup vs baseline: 1.0915x; 1.0915x over previous
//
#include <hip/hip_runtime.h>
#include <math.h>

// ---------------- CSR build ----------------

__global__ __launch_bounds__(256) void hist_k(const int* __restrict__ dst, int* __restrict__ deg, int E) {
    int e = blockIdx.x * 256 + threadIdx.x;
    if (e < E) atomicAdd(&deg[dst[e]], 1);
}

__global__ __launch_bounds__(256) void scanA_k(const int* __restrict__ deg, int* __restrict__ rowptr,
                                               int* __restrict__ partials, int N) {
    __shared__ int sh[256];
    int t = threadIdx.x;
    int base = blockIdx.x * 1024 + t * 4;
    int v0 = 0, v1 = 0, v2 = 0, v3 = 0;
    if (base + 0 < N) v0 = deg[base + 0];
    if (base + 1 < N) v1 = deg[base + 1];
    if (base + 2 < N) v2 = deg[base + 2];
    if (base + 3 < N) v3 = deg[base + 3];
    sh[t] = v0 + v1 + v2 + v3;
    __syncthreads();
    for (int off = 1; off < 256; off <<= 1) {
        int add = (t >= off) ? sh[t - off] : 0;
        __syncthreads();
        sh[t] += add;
        __syncthreads();
    }
    int run = (t > 0) ? sh[t - 1] : 0;
    if (base + 0 < N) rowptr[base + 0] = run; run += v0;
    if (base + 1 < N) rowptr[base + 1] = run; run += v1;
    if (base + 2 < N) rowptr[base + 2] = run; run += v2;
    if (base + 3 < N) rowptr[base + 3] = run;
    if (t == 255) partials[blockIdx.x] = sh[255];
}

__global__ void scanB_k(int* partials, int nch) {
    if (threadIdx.x == 0 && blockIdx.x == 0) {
        int run = 0;
        for (int i = 0; i < nch; ++i) { int x = partials[i]; partials[i] = run; run += x; }
        partials[nch] = run;
    }
}

__global__ __launch_bounds__(256) void addoff_k(int* __restrict__ rowptr, const int* __restrict__ partials,
                                                int N, int nch) {
    int t = threadIdx.x;
    int off = partials[blockIdx.x];
    int base = blockIdx.x * 1024;
    for (int i = 0; i < 4; ++i) {
        int idx = base + t + i * 256;
        if (idx < N) rowptr[idx] += off;
    }
    if (blockIdx.x == 0 && t == 0) rowptr[N] = partials[nch];
}

__global__ __launch_bounds__(256) void scatter_k(const int* __restrict__ src, const int* __restrict__ dst,
                                                 const int* __restrict__ rowptr, int* __restrict__ cnt,
                                                 int* __restrict__ srcid, int E) {
    int e = blockIdx.x * 256 + threadIdx.x;
    if (e < E) {
        int d = dst[e];
        int pos = rowptr[d] + atomicAdd(&cnt[d], 1);
        srcid[pos] = src[e];
    }
}

// ---------------- fused Q/K/V/skip projection (SGEMM, cols = [Wq|Wk|Wv|Ws] = 416) ----------------

__global__ __launch_bounds__(256) void qkvs_k(const float* __restrict__ X, int Cin, int N,
    const float* __restrict__ Wq, const float* __restrict__ bq,
    const float* __restrict__ Wk, const float* __restrict__ bk,
    const float* __restrict__ Wv, const float* __restrict__ bv,
    const float* __restrict__ Ws, const float* __restrict__ bs,
    float* __restrict__ q, float* __restrict__ k, float* __restrict__ v, float* __restrict__ sk)
{
    __shared__ float As[64][32];
    __shared__ float Bs[32][64];
    int tid = threadIdx.x;
    int ty = tid >> 4, tx = tid & 15;
    int row0 = blockIdx.x * 64;
    int c0 = blockIdx.y * 64;
    float acc[4][4];
#pragma unroll
    for (int i = 0; i < 4; ++i)
#pragma unroll
        for (int j = 0; j < 4; ++j) acc[i][j] = 0.f;

    for (int k0 = 0; k0 < Cin; k0 += 32) {
#pragma unroll
        for (int i = 0; i < 2; ++i) {
            int f4 = tid + i * 256;
            int r = f4 >> 3;
            int kk = (f4 & 7) << 2;
            float4 val = make_float4(0.f, 0.f, 0.f, 0.f);
            int gr = row0 + r;
            if (gr < N) val = *(const float4*)(X + (size_t)gr * Cin + k0 + kk);
            *(float4*)&As[r][kk] = val;
        }
#pragma unroll
        for (int i = 0; i < 2; ++i) {
            int f4 = tid + i * 256;
            int kk = f4 >> 4;
            int cc = (f4 & 15) << 2;
            int gc = c0 + cc;
            float4 val = make_float4(0.f, 0.f, 0.f, 0.f);
            const float* W = nullptr; int ow = 0, cb = 0;
            if (gc < 128)      { W = Wq; ow = 128; cb = gc; }
            else if (gc < 256) { W = Wk; ow = 128; cb = gc - 128; }
            else if (gc < 384) { W = Wv; ow = 128; cb = gc - 256; }
            else if (gc < 416) { W = Ws; ow = 32;  cb = gc - 384; }
            if (W) val = *(const float4*)(W + (size_t)(k0 + kk) * ow + cb);
            *(float4*)&Bs[kk][cc] = val;
        }
        __syncthreads();
#pragma unroll
        for (int kb = 0; kb < 32; kb += 4) {
            float a[4][4], b[4][4];
#pragma unroll
            for (int i = 0; i < 4; ++i) {
                float4 t4 = *(const float4*)&As[ty * 4 + i][kb];
                a[i][0] = t4.x; a[i][1] = t4.y; a[i][2] = t4.z; a[i][3] = t4.w;
            }
#pragma unroll
            for (int j = 0; j < 4; ++j) {
                float4 t4 = *(const float4*)&Bs[kb + j][tx * 4];
                b[j][0] = t4.x; b[j][1] = t4.y; b[j][2] = t4.z; b[j][3] = t4.w;
            }
#pragma unroll
            for (int i = 0; i < 4; ++i)
#pragma unroll
                for (int j = 0; j < 4; ++j)
#pragma unroll
                    for (int c = 0; c < 4; ++c)
                        acc[i][c] += a[i][j] * b[j][c];
        }
        __syncthreads();
    }

    int gc = c0 + tx * 4;
    const float* bias = nullptr; float* dstp = nullptr; int ow = 0, cb = 0;
    if (gc < 128)      { bias = bq; dstp = q;  ow = 128; cb = gc; }
    else if (gc < 256) { bias = bk; dstp = k;  ow = 128; cb = gc - 128; }
    else if (gc < 384) { bias = bv; dstp = v;  ow = 128; cb = gc - 256; }
    else if (gc < 416) { bias = bs; dstp = sk; ow = 32;  cb = gc - 384; }
    if (dstp) {
        float b0 = bias[cb], b1 = bias[cb + 1], b2 = bias[cb + 2], b3 = bias[cb + 3];
#pragma unroll
        for (int i = 0; i < 4; ++i) {
            int gr = row0 + ty * 4 + i;
            if (gr < N) {
                float4 o = make_float4(acc[i][0] + b0, acc[i][1] + b1, acc[i][2] + b2, acc[i][3] + b3);
                *(float4*)(dstp + (size_t)gr * ow + cb) = o;
            }
        }
    }
}

// ---------------- per-node attention over CSR (online softmax) ----------------
// 32 threads per node: lane l holds dims [l*4, l*4+4) i.e. head h=l>>3, sub s=l&7.
// Per-edge reduction: 3 shuffles within 8-lane head groups (vs 5 across 32 before);
// softmax state on 32 threads (vs 128) -> ~6.7x less shuffle-pipe, 4x less exp.

__global__ __launch_bounds__(256) void attn_k(const float* __restrict__ q, const float* __restrict__ k,
    const float* __restrict__ v, const float* __restrict__ sk,
    const int* __restrict__ rowptr, const int* __restrict__ srcid,
    float* __restrict__ out, int N)
{
    int grp = threadIdx.x >> 5;
    int n = blockIdx.x * 8 + grp;
    if (n >= N) return;
    int l = threadIdx.x & 31;
    int s = l & 7;
    const float scale = 0.17677669529663687f;  // 1/sqrt(32)

    float4 qv = *(const float4*)(q + (size_t)n * 128 + l * 4);
    float4 acc = make_float4(0.f, 0.f, 0.f, 0.f);
    float m = -INFINITY, lsum = 0.f;

    int e0 = rowptr[n], e1 = rowptr[n + 1];
    int sID = (e0 < e1) ? srcid[e0] : 0;
    for (int e = e0; e < e1; ++e) {
        int nextS = (e + 1 < e1) ? srcid[e + 1] : 0;
        const float* kp = k + (size_t)sID * 128 + l * 4;
        const float* vp = v + (size_t)sID * 128 + l * 4;
        float4 kv = *(const float4*)kp;
        float p = qv.x * kv.x + qv.y * kv.y + qv.z * kv.z + qv.w * kv.w;
        p += __shfl_xor(p, 1, 8);
        p += __shfl_xor(p, 2, 8);
        p += __shfl_xor(p, 4, 8);
        float logit = p * scale;
        float mn = fmaxf(m, logit);
        float ex = __expf(logit - mn);
        float sc = __expf(m - mn);
        float4 vv = *(const float4*)vp;
        lsum = lsum * sc + ex;
        acc.x = acc.x * sc + ex * vv.x;
        acc.y = acc.y * sc + ex * vv.y;
        acc.z = acc.z * sc + ex * vv.z;
        acc.w = acc.w * sc + ex * vv.w;
        m = mn;
        sID = nextS;
    }

    float inv = 0.25f / fmaxf(lsum, 1e-16f);
    float rx = acc.x * inv, ry = acc.y * inv, rz = acc.z * inv, rw = acc.w * inv;
    // head-mean: sum across h (lane stride 8) within the 32-lane group
    rx += __shfl_xor(rx, 8, 32);  rx += __shfl_xor(rx, 16, 32);
    ry += __shfl_xor(ry, 8, 32);  ry += __shfl_xor(ry, 16, 32);
    rz += __shfl_xor(rz, 8, 32);  rz += __shfl_xor(rz, 16, 32);
    rw += __shfl_xor(rw, 8, 32);  rw += __shfl_xor(rw, 16, 32);

    if (l < 8) {
        const float* skp = sk + (size_t)n * 32 + s * 4;
        float4 o = make_float4(fmaxf(rx + skp[0], 0.f), fmaxf(ry + skp[1], 0.f),
                               fmaxf(rz + skp[2], 0.f), fmaxf(rw + skp[3], 0.f));
        *(float4*)(out + (size_t)n * 32 + s * 4) = o;
    }
}

// ---------------- global mean pool (batch is sorted) ----------------

__global__ __launch_bounds__(256) void pool_k(const float* __restrict__ h, const int* __restrict__ batch,
                                              float* __restrict__ out, int N)
{
    int g = blockIdx.x;
    int t = threadIdx.x;
    int lo = 0, hi = N;
    while (lo < hi) { int mid = (lo + hi) >> 1; if (batch[mid] < g) lo = mid + 1; else hi = mid; }
    int start = lo;
    lo = 0; hi = N;
    while (lo < hi) { int mid = (lo + hi) >> 1; if (batch[mid] < g + 1) lo = mid + 1; else hi = mid; }
    int end = lo;
    int c = t & 31, r0 = t >> 5;
    float s = 0.f;
    for (int r = start + r0; r < end; r += 8) s += h[(size_t)r * 32 + c];
    __shared__ float sh[256];
    sh[t] = s;
    __syncthreads();
    if (t < 32) {
        float tot = sh[t] + sh[t + 32] + sh[t + 64] + sh[t + 96]
                  + sh[t + 128] + sh[t + 160] + sh[t + 192] + sh[t + 224];
        float cnt = (float)(end - start);
        out[(size_t)g * 32 + t] = tot / fmaxf(cnt, 1.f);
    }
}

// ---------------- launch ----------------

extern "C" void kernel_launch(void* const* d_in, const int* in_sizes, int n_in,
                              void* d_out, int out_size, void* d_ws, size_t ws_size,
                              hipStream_t stream) {
    const float* x   = (const float*)d_in[0];
    const int* ei    = (const int*)d_in[1];
    const int* batch = (const int*)d_in[2];
    const float *Wq1 = (const float*)d_in[3],  *bq1 = (const float*)d_in[4];
    const float *Wk1 = (const float*)d_in[5],  *bk1 = (const float*)d_in[6];
    const float *Wv1 = (const float*)d_in[7],  *bv1 = (const float*)d_in[8];
    const float *Ws1 = (const float*)d_in[9],  *bs1 = (const float*)d_in[10];
    const float *Wq2 = (const float*)d_in[11], *bq2 = (const float*)d_in[12];
    const float *Wk2 = (const float*)d_in[13], *bk2 = (const float*)d_in[14];
    const float *Wv2 = (const float*)d_in[15], *bv2 = (const float*)d_in[16];
    const float *Ws2 = (const float*)d_in[17], *bs2 = (const float*)d_in[18];
    float* out = (float*)d_out;

    int N = in_sizes[0] / 128;
    int E = in_sizes[1] / 2;
    const int* src = ei;
    const int* dst = ei + E;

    char* ws = (char*)d_ws;
    size_t off = 0;
    auto alloc = [&](size_t bytes) -> void* {
        void* p = ws + off;
        off += (bytes + 255) & ~(size_t)255;
        return p;
    };
    int* deg      = (int*)alloc((size_t)N * 4);
    int* cnt      = (int*)alloc((size_t)N * 4);
    int* rowptr   = (int*)alloc(((size_t)N + 1) * 4);
    int* partials = (int*)alloc(4096);
    int* srcid    = (int*)alloc((size_t)E * 4);
    float* q      = (float*)alloc((size_t)N * 128 * 4);
    float* k      = (float*)alloc((size_t)N * 128 * 4);
    float* v      = (float*)alloc((size_t)N * 128 * 4);
    float* sk     = (float*)alloc((size_t)N * 32 * 4);
    float* h1     = (float*)alloc((size_t)N * 32 * 4);
    float* h2     = (float*)alloc((size_t)N * 32 * 4);

    hipMemsetAsync(deg, 0, (size_t)N * 4, stream);
    hipMemsetAsync(cnt, 0, (size_t)N * 4, stream);

    int nch = (N + 1023) / 1024;
    hist_k<<<(E + 255) / 256, 256, 0, stream>>>(dst, deg, E);
    scanA_k<<<nch, 256, 0, stream>>>(deg, rowptr, partials, N);
    scanB_k<<<1, 64, 0, stream>>>(partials, nch);
    addoff_k<<<nch, 256, 0, stream>>>(rowptr, partials, N, nch);
    scatter_k<<<(E + 255) / 256, 256, 0, stream>>>(src, dst, rowptr, cnt, srcid, E);

    dim3 g1((N + 63) / 64, 7);
    qkvs_k<<<g1, 256, 0, stream>>>(x, 128, N, Wq1, bq1, Wk1, bk1, Wv1, bv1, Ws1, bs1, q, k, v, sk);
    attn_k<<<(N + 7) / 8, 256, 0, stream>>>(q, k, v, sk, rowptr, srcid, h1, N);
    qkvs_k<<<g1, 256, 0, stream>>>(h1, 32, N, Wq2, bq2, Wk2, bk2, Wv2, bv2, Ws2, bs2, q, k, v, sk);
    attn_k<<<(N + 7) / 8, 256, 0, stream>>>(q, k, v, sk, rowptr, srcid, h2, N);
    pool_k<<<512, 256, 0, stream>>>(h2, batch, out, N);
}

// Round 4
// 676.929 us; speedup vs baseline: 1.3647x; 1.2504x over previous
//
#include <hip/hip_runtime.h>
#include <math.h>

__device__ __forceinline__ float b2f(unsigned short u) {
    union { unsigned u32; float f; } x; x.u32 = (unsigned)u << 16; return x.f;
}
__device__ __forceinline__ unsigned short f2b(float f) {
    union { float f; unsigned u32; } x; x.f = f;
    unsigned u = x.u32;
    unsigned r = (u + 0x7fffu + ((u >> 16) & 1u)) >> 16;   // RNE
    return (unsigned short)r;
}

// ---------------- CSR build ----------------

__global__ __launch_bounds__(256) void hist_k(const int* __restrict__ dst, int* __restrict__ deg, int E) {
    int e = blockIdx.x * 256 + threadIdx.x;
    if (e < E) atomicAdd(&deg[dst[e]], 1);
}

__global__ __launch_bounds__(256) void scanA_k(const int* __restrict__ deg, int* __restrict__ rowptr,
                                               int* __restrict__ partials, int N) {
    __shared__ int sh[256];
    int t = threadIdx.x;
    int base = blockIdx.x * 1024 + t * 4;
    int v0 = 0, v1 = 0, v2 = 0, v3 = 0;
    if (base + 0 < N) v0 = deg[base + 0];
    if (base + 1 < N) v1 = deg[base + 1];
    if (base + 2 < N) v2 = deg[base + 2];
    if (base + 3 < N) v3 = deg[base + 3];
    sh[t] = v0 + v1 + v2 + v3;
    __syncthreads();
    for (int off = 1; off < 256; off <<= 1) {
        int add = (t >= off) ? sh[t - off] : 0;
        __syncthreads();
        sh[t] += add;
        __syncthreads();
    }
    int run = (t > 0) ? sh[t - 1] : 0;
    if (base + 0 < N) rowptr[base + 0] = run; run += v0;
    if (base + 1 < N) rowptr[base + 1] = run; run += v1;
    if (base + 2 < N) rowptr[base + 2] = run; run += v2;
    if (base + 3 < N) rowptr[base + 3] = run;
    if (t == 255) partials[blockIdx.x] = sh[255];
}

__global__ void scanB_k(int* partials, int nch) {
    if (threadIdx.x == 0 && blockIdx.x == 0) {
        int run = 0;
        for (int i = 0; i < nch; ++i) { int x = partials[i]; partials[i] = run; run += x; }
        partials[nch] = run;
    }
}

__global__ __launch_bounds__(256) void addoff_k(int* __restrict__ rowptr, const int* __restrict__ partials,
                                                int N, int nch) {
    int t = threadIdx.x;
    int off = partials[blockIdx.x];
    int base = blockIdx.x * 1024;
    for (int i = 0; i < 4; ++i) {
        int idx = base + t + i * 256;
        if (idx < N) rowptr[idx] += off;
    }
    if (blockIdx.x == 0 && t == 0) rowptr[N] = partials[nch];
}

__global__ __launch_bounds__(256) void scatter_k(const int* __restrict__ src, const int* __restrict__ dst,
                                                 const int* __restrict__ rowptr, int* __restrict__ cnt,
                                                 int* __restrict__ srcid, int E) {
    int e = blockIdx.x * 256 + threadIdx.x;
    if (e < E) {
        int d = dst[e];
        int pos = rowptr[d] + atomicAdd(&cnt[d], 1);
        srcid[pos] = src[e];
    }
}

// ---------------- fused Q/K/V/skip projection (SGEMM, cols = [Wq|Wk|Wv|Ws] = 416) ----------------
// k and v are written as bf16 tables (RNE); q and skip stay f32.

__global__ __launch_bounds__(256) void qkvs_k(const float* __restrict__ X, int Cin, int N,
    const float* __restrict__ Wq, const float* __restrict__ bq,
    const float* __restrict__ Wk, const float* __restrict__ bk,
    const float* __restrict__ Wv, const float* __restrict__ bv,
    const float* __restrict__ Ws, const float* __restrict__ bs,
    float* __restrict__ q, unsigned short* __restrict__ kb,
    unsigned short* __restrict__ vb, float* __restrict__ sk)
{
    __shared__ float As[64][32];
    __shared__ float Bs[32][64];
    int tid = threadIdx.x;
    int ty = tid >> 4, tx = tid & 15;
    int row0 = blockIdx.x * 64;
    int c0 = blockIdx.y * 64;
    float acc[4][4];
#pragma unroll
    for (int i = 0; i < 4; ++i)
#pragma unroll
        for (int j = 0; j < 4; ++j) acc[i][j] = 0.f;

    for (int k0 = 0; k0 < Cin; k0 += 32) {
#pragma unroll
        for (int i = 0; i < 2; ++i) {
            int f4 = tid + i * 256;
            int r = f4 >> 3;
            int kk = (f4 & 7) << 2;
            float4 val = make_float4(0.f, 0.f, 0.f, 0.f);
            int gr = row0 + r;
            if (gr < N) val = *(const float4*)(X + (size_t)gr * Cin + k0 + kk);
            *(float4*)&As[r][kk] = val;
        }
#pragma unroll
        for (int i = 0; i < 2; ++i) {
            int f4 = tid + i * 256;
            int kk = f4 >> 4;
            int cc = (f4 & 15) << 2;
            int gc = c0 + cc;
            float4 val = make_float4(0.f, 0.f, 0.f, 0.f);
            const float* W = nullptr; int ow = 0, cb = 0;
            if (gc < 128)      { W = Wq; ow = 128; cb = gc; }
            else if (gc < 256) { W = Wk; ow = 128; cb = gc - 128; }
            else if (gc < 384) { W = Wv; ow = 128; cb = gc - 256; }
            else if (gc < 416) { W = Ws; ow = 32;  cb = gc - 384; }
            if (W) val = *(const float4*)(W + (size_t)(k0 + kk) * ow + cb);
            *(float4*)&Bs[kk][cc] = val;
        }
        __syncthreads();
#pragma unroll
        for (int kb2 = 0; kb2 < 32; kb2 += 4) {
            float a[4][4], b[4][4];
#pragma unroll
            for (int i = 0; i < 4; ++i) {
                float4 t4 = *(const float4*)&As[ty * 4 + i][kb2];
                a[i][0] = t4.x; a[i][1] = t4.y; a[i][2] = t4.z; a[i][3] = t4.w;
            }
#pragma unroll
            for (int j = 0; j < 4; ++j) {
                float4 t4 = *(const float4*)&Bs[kb2 + j][tx * 4];
                b[j][0] = t4.x; b[j][1] = t4.y; b[j][2] = t4.z; b[j][3] = t4.w;
            }
#pragma unroll
            for (int i = 0; i < 4; ++i)
#pragma unroll
                for (int j = 0; j < 4; ++j)
#pragma unroll
                    for (int c = 0; c < 4; ++c)
                        acc[i][c] += a[i][j] * b[j][c];
        }
        __syncthreads();
    }

    int gc = c0 + tx * 4;
    // dest selector: 0=q(f32), 1=k(bf16), 2=v(bf16), 3=skip(f32)
    int sel; const float* bias; int cb;
    if (gc < 128)      { sel = 0; bias = bq; cb = gc; }
    else if (gc < 256) { sel = 1; bias = bk; cb = gc - 128; }
    else if (gc < 384) { sel = 2; bias = bv; cb = gc - 256; }
    else               { sel = 3; bias = bs; cb = gc - 384; }
    if (gc < 416) {
        float b0 = bias[cb], b1 = bias[cb + 1], b2 = bias[cb + 2], b3 = bias[cb + 3];
#pragma unroll
        for (int i = 0; i < 4; ++i) {
            int gr = row0 + ty * 4 + i;
            if (gr < N) {
                float o0 = acc[i][0] + b0, o1 = acc[i][1] + b1;
                float o2 = acc[i][2] + b2, o3 = acc[i][3] + b3;
                if (sel == 0) {
                    *(float4*)(q + (size_t)gr * 128 + cb) = make_float4(o0, o1, o2, o3);
                } else if (sel == 1) {
                    ushort4 u = make_ushort4(f2b(o0), f2b(o1), f2b(o2), f2b(o3));
                    *(ushort4*)(kb + (size_t)gr * 128 + cb) = u;
                } else if (sel == 2) {
                    ushort4 u = make_ushort4(f2b(o0), f2b(o1), f2b(o2), f2b(o3));
                    *(ushort4*)(vb + (size_t)gr * 128 + cb) = u;
                } else {
                    *(float4*)(sk + (size_t)gr * 32 + cb) = make_float4(o0, o1, o2, o3);
                }
            }
        }
    }
}

// ---------------- per-node attention over CSR (online softmax) ----------------
// 32 threads per node: lane l holds dims [l*4, l*4+4), head h=l>>3, sub s=l&7.
// k/v gathers are bf16 rows (256 B per row per 32-lane group).

__global__ __launch_bounds__(256) void attn_k(const float* __restrict__ q,
    const unsigned short* __restrict__ k, const unsigned short* __restrict__ v,
    const float* __restrict__ sk,
    const int* __restrict__ rowptr, const int* __restrict__ srcid,
    float* __restrict__ out, int N)
{
    int grp = threadIdx.x >> 5;
    int n = blockIdx.x * 8 + grp;
    if (n >= N) return;
    int l = threadIdx.x & 31;
    int s = l & 7;
    const float scale = 0.17677669529663687f;  // 1/sqrt(32)

    float4 qv = *(const float4*)(q + (size_t)n * 128 + l * 4);
    float4 acc = make_float4(0.f, 0.f, 0.f, 0.f);
    float m = -INFINITY, lsum = 0.f;

    int e0 = rowptr[n], e1 = rowptr[n + 1];
    int sID = (e0 < e1) ? srcid[e0] : 0;
    for (int e = e0; e < e1; ++e) {
        int nextS = (e + 1 < e1) ? srcid[e + 1] : 0;
        ushort4 kraw = *(const ushort4*)(k + (size_t)sID * 128 + l * 4);
        ushort4 vraw = *(const ushort4*)(v + (size_t)sID * 128 + l * 4);
        float p = qv.x * b2f(kraw.x) + qv.y * b2f(kraw.y)
                + qv.z * b2f(kraw.z) + qv.w * b2f(kraw.w);
        p += __shfl_xor(p, 1, 8);
        p += __shfl_xor(p, 2, 8);
        p += __shfl_xor(p, 4, 8);
        float logit = p * scale;
        float mn = fmaxf(m, logit);
        float ex = __expf(logit - mn);
        float sc = __expf(m - mn);
        lsum = lsum * sc + ex;
        acc.x = acc.x * sc + ex * b2f(vraw.x);
        acc.y = acc.y * sc + ex * b2f(vraw.y);
        acc.z = acc.z * sc + ex * b2f(vraw.z);
        acc.w = acc.w * sc + ex * b2f(vraw.w);
        m = mn;
        sID = nextS;
    }

    float inv = 0.25f / fmaxf(lsum, 1e-16f);
    float rx = acc.x * inv, ry = acc.y * inv, rz = acc.z * inv, rw = acc.w * inv;
    // head-mean: sum across h (lane stride 8) within the 32-lane group
    rx += __shfl_xor(rx, 8, 32);  rx += __shfl_xor(rx, 16, 32);
    ry += __shfl_xor(ry, 8, 32);  ry += __shfl_xor(ry, 16, 32);
    rz += __shfl_xor(rz, 8, 32);  rz += __shfl_xor(rz, 16, 32);
    rw += __shfl_xor(rw, 8, 32);  rw += __shfl_xor(rw, 16, 32);

    if (l < 8) {
        const float* skp = sk + (size_t)n * 32 + s * 4;
        float4 o = make_float4(fmaxf(rx + skp[0], 0.f), fmaxf(ry + skp[1], 0.f),
                               fmaxf(rz + skp[2], 0.f), fmaxf(rw + skp[3], 0.f));
        *(float4*)(out + (size_t)n * 32 + s * 4) = o;
    }
}

// ---------------- global mean pool (batch is sorted) ----------------

__global__ __launch_bounds__(256) void pool_k(const float* __restrict__ h, const int* __restrict__ batch,
                                              float* __restrict__ out, int N)
{
    int g = blockIdx.x;
    int t = threadIdx.x;
    int lo = 0, hi = N;
    while (lo < hi) { int mid = (lo + hi) >> 1; if (batch[mid] < g) lo = mid + 1; else hi = mid; }
    int start = lo;
    lo = 0; hi = N;
    while (lo < hi) { int mid = (lo + hi) >> 1; if (batch[mid] < g + 1) lo = mid + 1; else hi = mid; }
    int end = lo;
    int c = t & 31, r0 = t >> 5;
    float s = 0.f;
    for (int r = start + r0; r < end; r += 8) s += h[(size_t)r * 32 + c];
    __shared__ float sh[256];
    sh[t] = s;
    __syncthreads();
    if (t < 32) {
        float tot = sh[t] + sh[t + 32] + sh[t + 64] + sh[t + 96]
                  + sh[t + 128] + sh[t + 160] + sh[t + 192] + sh[t + 224];
        float cnt = (float)(end - start);
        out[(size_t)g * 32 + t] = tot / fmaxf(cnt, 1.f);
    }
}

// ---------------- launch ----------------

extern "C" void kernel_launch(void* const* d_in, const int* in_sizes, int n_in,
                              void* d_out, int out_size, void* d_ws, size_t ws_size,
                              hipStream_t stream) {
    const float* x   = (const float*)d_in[0];
    const int* ei    = (const int*)d_in[1];
    const int* batch = (const int*)d_in[2];
    const float *Wq1 = (const float*)d_in[3],  *bq1 = (const float*)d_in[4];
    const float *Wk1 = (const float*)d_in[5],  *bk1 = (const float*)d_in[6];
    const float *Wv1 = (const float*)d_in[7],  *bv1 = (const float*)d_in[8];
    const float *Ws1 = (const float*)d_in[9],  *bs1 = (const float*)d_in[10];
    const float *Wq2 = (const float*)d_in[11], *bq2 = (const float*)d_in[12];
    const float *Wk2 = (const float*)d_in[13], *bk2 = (const float*)d_in[14];
    const float *Wv2 = (const float*)d_in[15], *bv2 = (const float*)d_in[16];
    const float *Ws2 = (const float*)d_in[17], *bs2 = (const float*)d_in[18];
    float* out = (float*)d_out;

    int N = in_sizes[0] / 128;
    int E = in_sizes[1] / 2;
    const int* src = ei;
    const int* dst = ei + E;

    char* ws = (char*)d_ws;
    size_t off = 0;
    auto alloc = [&](size_t bytes) -> void* {
        void* p = ws + off;
        off += (bytes + 255) & ~(size_t)255;
        return p;
    };
    int* deg      = (int*)alloc((size_t)N * 4);
    int* cnt      = (int*)alloc((size_t)N * 4);
    int* rowptr   = (int*)alloc(((size_t)N + 1) * 4);
    int* partials = (int*)alloc(4096);
    int* srcid    = (int*)alloc((size_t)E * 4);
    float* q            = (float*)alloc((size_t)N * 128 * 4);
    unsigned short* kb  = (unsigned short*)alloc((size_t)N * 128 * 2);
    unsigned short* vb  = (unsigned short*)alloc((size_t)N * 128 * 2);
    float* sk     = (float*)alloc((size_t)N * 32 * 4);
    float* h1     = (float*)alloc((size_t)N * 32 * 4);
    float* h2     = (float*)alloc((size_t)N * 32 * 4);

    hipMemsetAsync(deg, 0, (size_t)N * 4, stream);
    hipMemsetAsync(cnt, 0, (size_t)N * 4, stream);

    int nch = (N + 1023) / 1024;
    hist_k<<<(E + 255) / 256, 256, 0, stream>>>(dst, deg, E);
    scanA_k<<<nch, 256, 0, stream>>>(deg, rowptr, partials, N);
    scanB_k<<<1, 64, 0, stream>>>(partials, nch);
    addoff_k<<<nch, 256, 0, stream>>>(rowptr, partials, N, nch);
    scatter_k<<<(E + 255) / 256, 256, 0, stream>>>(src, dst, rowptr, cnt, srcid, E);

    dim3 g1((N + 63) / 64, 7);
    qkvs_k<<<g1, 256, 0, stream>>>(x, 128, N, Wq1, bq1, Wk1, bk1, Wv1, bv1, Ws1, bs1, q, kb, vb, sk);
    attn_k<<<(N + 7) / 8, 256, 0, stream>>>(q, kb, vb, sk, rowptr, srcid, h1, N);
    qkvs_k<<<g1, 256, 0, stream>>>(h1, 32, N, Wq2, bq2, Wk2, bk2, Wv2, bv2, Ws2, bs2, q, kb, vb, sk);
    attn_k<<<(N + 7) / 8, 256, 0, stream>>>(q, kb, vb, sk, rowptr, srcid, h2, N);
    pool_k<<<512, 256, 0, stream>>>(h2, batch, out, N);
}